// Round 1
// baseline (78.031 us; speedup 1.0000x reference)
//
#include <hip/hip_runtime.h>
#include <hip/hip_bf16.h>
#include <stdint.h>

// Problem: B=1024, IN=20000, NG=64, GIN=512, H1=256, GS=128
// o = x[:,idx] @ (W1@W2) + (b1@W2 + b2)   -- linear-linear collapse
//
// ws layout: G bf16 [64][1024][512] @0 (64MiB), Wc bf16 [64][128][512] @64MiB (8MiB),
//            bias2 f32 [64][128] @72MiB (32KB). Requires ws_size >= 72MiB+32KB.

typedef __attribute__((ext_vector_type(4))) float f32x4;
typedef __attribute__((ext_vector_type(8))) __bf16 bf16x8;
typedef __attribute__((ext_vector_type(8))) uint16_t u16x8;

__device__ __forceinline__ uint16_t f2bf(float f) {
    uint32_t u = __float_as_uint(f);
    u += 0x7FFFu + ((u >> 16) & 1u);   // RNE
    return (uint16_t)(u >> 16);
}

// ---------------- K1: gather. One block per batch row b. ----------------
// Stage x[b,:] (80KB f32 -> 40KB bf16) in LDS coalesced, then 32768 LDS
// gathers, write G[g][b][k] bf16 coalesced (u32 = 2 bf16 per thread).
__global__ __launch_bounds__(256) void k_gather(const float* __restrict__ x,
                                                const int* __restrict__ idx,
                                                uint32_t* __restrict__ G32) {
    __shared__ uint16_t sh[20000];
    const int b = blockIdx.x;
    const int t = threadIdx.x;
    const f32x4* xr = (const f32x4*)(x + (size_t)b * 20000);
    for (int i = t; i < 5000; i += 256) {
        f32x4 v = xr[i];
        uint64_t p = (uint64_t)f2bf(v[0]) | ((uint64_t)f2bf(v[1]) << 16)
                   | ((uint64_t)f2bf(v[2]) << 32) | ((uint64_t)f2bf(v[3]) << 48);
        *(uint64_t*)&sh[i * 4] = p;
    }
    __syncthreads();
    const int2* idx2 = (const int2*)idx;
    const size_t bbase = (size_t)b * 256;
    #pragma unroll 4
    for (int i = t; i < 16384; i += 256) {     // i indexes (g, k-pair)
        int2 iv = idx2[i];
        uint32_t lo = sh[iv.x];
        uint32_t hi = sh[iv.y];
        int g = i >> 8, kp = i & 255;
        G32[(size_t)g * 262144 + bbase + kp] = lo | (hi << 16);
    }
}

// ---------------- K2: Wc[g][n][k] = (W1[g] @ W2[g])^T in bf16 ----------------
// Per block: one (g, k-tile of 128). M=128(k) x N=128(n), K=256(h), BK=32.
// A = W1 rows (h contiguous) -> LDS [128][40]; B = W2 tile [h][n] -> LDS [32][132]
// (B-frag assembled via 8 scalar u16 reads; pad 132 chosen conflict-free).
__global__ __launch_bounds__(256) void k_wprep(const float* __restrict__ W1,
                                               const float* __restrict__ W2,
                                               uint16_t* __restrict__ Wc) {
    __shared__ uint16_t As[128 * 40];
    __shared__ uint16_t Bs[32 * 132];
    const int g = blockIdx.x >> 2, mt = blockIdx.x & 3;
    const int t = threadIdx.x;
    const int wid = t >> 6, l = t & 63;
    const int wm = wid >> 1, wn = wid & 1;
    const int q = l >> 4, lm = l & 15;
    const float* W1g = W1 + ((size_t)g * 512 + (size_t)mt * 128) * 256;
    const float* W2g = W2 + (size_t)g * 256 * 128;
    f32x4 acc[4][4];
    #pragma unroll
    for (int mi = 0; mi < 4; ++mi)
        #pragma unroll
        for (int ni = 0; ni < 4; ++ni) {
            f32x4 z = {0.f, 0.f, 0.f, 0.f};
            acc[mi][ni] = z;
        }

    for (int kt = 0; kt < 8; ++kt) {
        __syncthreads();
        #pragma unroll
        for (int i = 0; i < 4; ++i) {          // A: 128 x 32 f32 -> bf16
            int f4 = t + i * 256;
            int m = f4 >> 3, c4 = f4 & 7;
            f32x4 v = *(const f32x4*)(W1g + (size_t)m * 256 + kt * 32 + c4 * 4);
            uint64_t p = (uint64_t)f2bf(v[0]) | ((uint64_t)f2bf(v[1]) << 16)
                       | ((uint64_t)f2bf(v[2]) << 32) | ((uint64_t)f2bf(v[3]) << 48);
            *(uint64_t*)&As[m * 40 + c4 * 4] = p;
        }
        #pragma unroll
        for (int i = 0; i < 4; ++i) {          // B: 32(h) x 128(n)
            int f4 = t + i * 256;
            int h = f4 >> 5, n4 = f4 & 31;
            f32x4 v = *(const f32x4*)(W2g + (size_t)(kt * 32 + h) * 128 + n4 * 4);
            uint64_t p = (uint64_t)f2bf(v[0]) | ((uint64_t)f2bf(v[1]) << 16)
                       | ((uint64_t)f2bf(v[2]) << 32) | ((uint64_t)f2bf(v[3]) << 48);
            *(uint64_t*)&Bs[h * 132 + n4 * 4] = p;
        }
        __syncthreads();
        bf16x8 a[4];
        #pragma unroll
        for (int mi = 0; mi < 4; ++mi)
            a[mi] = *(const bf16x8*)&As[(wm * 64 + mi * 16 + lm) * 40 + q * 8];
        #pragma unroll
        for (int ni = 0; ni < 4; ++ni) {
            int n = wn * 64 + ni * 16 + lm;
            u16x8 bu;
            #pragma unroll
            for (int j = 0; j < 8; ++j) bu[j] = Bs[(q * 8 + j) * 132 + n];
            bf16x8 bv = __builtin_bit_cast(bf16x8, bu);
            #pragma unroll
            for (int mi = 0; mi < 4; ++mi)
                acc[mi][ni] = __builtin_amdgcn_mfma_f32_16x16x32_bf16(a[mi], bv, acc[mi][ni], 0, 0, 0);
        }
    }
    // store Wc[g][n][k] bf16; lane holds 4 consecutive k per frag reg -> 8B stores
    uint16_t* Wcg = Wc + (size_t)g * 128 * 512;
    #pragma unroll
    for (int mi = 0; mi < 4; ++mi) {
        int k0 = mt * 128 + wm * 64 + mi * 16 + q * 4;
        #pragma unroll
        for (int ni = 0; ni < 4; ++ni) {
            int n = wn * 64 + ni * 16 + lm;
            f32x4 c = acc[mi][ni];
            uint64_t p = (uint64_t)f2bf(c[0]) | ((uint64_t)f2bf(c[1]) << 16)
                       | ((uint64_t)f2bf(c[2]) << 32) | ((uint64_t)f2bf(c[3]) << 48);
            *(uint64_t*)&Wcg[(size_t)n * 512 + k0] = p;
        }
    }
}

// ---------------- K3: bias2[g][n] = b1[g] @ W2[g,:,n] + b2[g][n] (f32) ----------------
__global__ __launch_bounds__(128) void k_bias(const float* __restrict__ b1,
                                              const float* __restrict__ W2,
                                              const float* __restrict__ b2,
                                              float* __restrict__ bias2) {
    const int g = blockIdx.x, n = threadIdx.x;
    const float* w = W2 + (size_t)g * 256 * 128 + n;
    const float* bb = b1 + g * 256;
    float s = b2[g * 128 + n];
    for (int h = 0; h < 256; ++h) s += bb[h] * w[(size_t)h * 128];
    bias2[g * 128 + n] = s;
}

// ---------------- K4: out[b, g*128+n] = G[g] @ Wc[g]^T + bias2[g] ----------------
// m97-style: 128x128 tile, BK=64, global_load_lds(16), linear LDS [row][64] with
// XOR swizzle baked into the per-lane GLOBAL source (rule #21), swizzled ds_read.
__global__ __launch_bounds__(256) void k_gemm(const uint16_t* __restrict__ G,
                                              const uint16_t* __restrict__ Wc,
                                              const float* __restrict__ bias2,
                                              float* __restrict__ out) {
    __shared__ uint16_t sh[16384];             // A: [0,8192), B: [8192,16384) elems
    uint16_t* As = sh;
    uint16_t* Bs = sh + 8192;
    const int g = blockIdx.x >> 3, mt = blockIdx.x & 7;
    const int t = threadIdx.x;
    const int wid = t >> 6, l = t & 63;
    const int wm = wid >> 1, wn = wid & 1;
    const int q = l >> 4, lm = l & 15;
    const int lrow = l >> 3;                     // 8 rows per 1KB chunk
    const int lcolsw = ((l & 7) ^ lrow) * 8;     // inverse-swizzled global col (elems)
    const uint16_t* Ga = G + (size_t)g * 524288 + (size_t)mt * 128 * 512;
    const uint16_t* Wa = Wc + (size_t)g * 65536;

    f32x4 acc[4][4];
    #pragma unroll
    for (int mi = 0; mi < 4; ++mi)
        #pragma unroll
        for (int ni = 0; ni < 4; ++ni) {
            f32x4 z = {0.f, 0.f, 0.f, 0.f};
            acc[mi][ni] = z;
        }

    for (int kt = 0; kt < 8; ++kt) {
        __syncthreads();                          // prev compute done before overwrite
        #pragma unroll
        for (int r = 0; r < 4; ++r) {
            const int rowbase = wid * 8 + r * 32; // wave-uniform, multiple of 8
            const uint16_t* sA = Ga + (size_t)(rowbase + lrow) * 512 + kt * 64 + lcolsw;
            const uint16_t* sB = Wa + (size_t)(rowbase + lrow) * 512 + kt * 64 + lcolsw;
            __builtin_amdgcn_global_load_lds(
                (const __attribute__((address_space(1))) void*)sA,
                (__attribute__((address_space(3))) void*)(As + rowbase * 64), 16, 0, 0);
            __builtin_amdgcn_global_load_lds(
                (const __attribute__((address_space(1))) void*)sB,
                (__attribute__((address_space(3))) void*)(Bs + rowbase * 64), 16, 0, 0);
        }
        __syncthreads();                          // drains vmcnt -> data visible
        #pragma unroll
        for (int kk = 0; kk < 2; ++kk) {
            bf16x8 a[4], b[4];
            #pragma unroll
            for (int mi = 0; mi < 4; ++mi) {
                int row = wm * 64 + mi * 16 + lm;
                int off = row * 64 + ((kk * 32 + q * 8) ^ ((lm & 7) * 8));
                a[mi] = *(const bf16x8*)&As[off];
            }
            #pragma unroll
            for (int ni = 0; ni < 4; ++ni) {
                int row = wn * 64 + ni * 16 + lm;
                int off = row * 64 + ((kk * 32 + q * 8) ^ ((lm & 7) * 8));
                b[ni] = *(const bf16x8*)&Bs[off];
            }
            #pragma unroll
            for (int mi = 0; mi < 4; ++mi)
                #pragma unroll
                for (int ni = 0; ni < 4; ++ni)
                    acc[mi][ni] = __builtin_amdgcn_mfma_f32_16x16x32_bf16(a[mi], b[ni], acc[mi][ni], 0, 0, 0);
        }
    }
    // epilogue: C/D layout col=lane&15, row=(lane>>4)*4+reg
    float bn[4];
    #pragma unroll
    for (int ni = 0; ni < 4; ++ni) bn[ni] = bias2[g * 128 + wn * 64 + ni * 16 + lm];
    #pragma unroll
    for (int mi = 0; mi < 4; ++mi)
        #pragma unroll
        for (int ni = 0; ni < 4; ++ni) {
            int col = g * 128 + wn * 64 + ni * 16 + lm;
            #pragma unroll
            for (int r = 0; r < 4; ++r) {
                int brow = mt * 128 + wm * 64 + mi * 16 + q * 4 + r;
                out[(size_t)brow * 8192 + col] = acc[mi][ni][r] + bn[ni];
            }
        }
}

extern "C" void kernel_launch(void* const* d_in, const int* in_sizes, int n_in,
                              void* d_out, int out_size, void* d_ws, size_t ws_size,
                              hipStream_t stream) {
    (void)in_sizes; (void)n_in; (void)out_size; (void)ws_size;
    const float* x   = (const float*)d_in[0];
    const int*   idx = (const int*)d_in[1];
    const float* W1  = (const float*)d_in[2];
    const float* b1  = (const float*)d_in[3];
    const float* W2  = (const float*)d_in[4];
    const float* b2  = (const float*)d_in[5];
    float* out = (float*)d_out;

    uint16_t* G     = (uint16_t*)d_ws;                                  // 64 MiB
    uint16_t* Wc    = (uint16_t*)((char*)d_ws + (size_t)(64 << 20));    //  8 MiB
    float*    bias2 = (float*)   ((char*)d_ws + (size_t)(72 << 20));    // 32 KiB

    k_gather<<<1024, 256, 0, stream>>>(x, idx, (uint32_t*)G);
    k_wprep <<<256,  256, 0, stream>>>(W1, W2, Wc);
    k_bias  <<<64,   128, 0, stream>>>(b1, W2, b2, bias2);
    k_gemm  <<<512,  256, 0, stream>>>(G, Wc, bias2, out);
}

// Round 2
// 70.304 us; speedup vs baseline: 1.1099x; 1.1099x over previous
//
#include <hip/hip_runtime.h>
#include <hip/hip_bf16.h>
#include <stdint.h>

// Problem: B=1024, IN=20000, NG=64, GIN=512, H1=256, GS=128
// o = x[:,idx] @ (W1@W2) + (b1@W2 + b2)   -- linear-linear collapse
//
// ws layout: G bf16 [64][1024][512] @0 (64MiB), Wc bf16 [64][128][512] @64MiB (8MiB),
//            bias2 f32 [64][128] @72MiB (32KB). Requires ws_size >= 72MiB+32KB.
//
// R2: fat prep kernel (wprep | bias | gather) @512 threads; gather widened to
// int4 idx + uint2 stores. k_gemm unchanged from R1 (verified).

typedef __attribute__((ext_vector_type(4))) float f32x4;
typedef __attribute__((ext_vector_type(8))) __bf16 bf16x8;
typedef __attribute__((ext_vector_type(8))) uint16_t u16x8;

__device__ __forceinline__ uint16_t f2bf(float f) {
    uint32_t u = __float_as_uint(f);
    u += 0x7FFFu + ((u >> 16) & 1u);   // RNE
    return (uint16_t)(u >> 16);
}

__device__ __forceinline__ uint64_t pack4bf(f32x4 v) {
    return (uint64_t)f2bf(v[0]) | ((uint64_t)f2bf(v[1]) << 16)
         | ((uint64_t)f2bf(v[2]) << 32) | ((uint64_t)f2bf(v[3]) << 48);
}

// ---------------- fat prep kernel ----------------
// blocks [0,256):   wprep  -- Wc[g][n][k] = (W1[g]@W2[g])^T bf16, g=bid>>2, ktile=bid&3
// blocks [256,320): bias   -- bias2[g][n] = b1[g]@W2[g,:,n] + b2[g][n]
// blocks [320,1344): gather-- G[g][b][k] = bf16(x[b, idx[g][k]]), b=bid-320
__global__ __launch_bounds__(512) void k_prep(const float* __restrict__ x,
                                              const int* __restrict__ idx,
                                              const float* __restrict__ W1,
                                              const float* __restrict__ b1,
                                              const float* __restrict__ W2,
                                              const float* __restrict__ b2,
                                              uint16_t* __restrict__ Wc,
                                              float* __restrict__ bias2,
                                              uint32_t* __restrict__ G32) {
    __shared__ __align__(16) uint64_t smem8[5000];   // 40000 B, aliased per role
    const int bid = blockIdx.x;
    const int t = threadIdx.x;

    if (bid < 256) {
        // ---- wprep: M=128(k-rows of Wc^T) x N=128(n), K=256(h), BK=32, 8 waves 4x2 ----
        uint16_t* As = (uint16_t*)smem8;            // [128][40]
        uint16_t* Bs = As + 5120;                   // [32][132]
        const int g = bid >> 2, mt = bid & 3;
        const int wid = t >> 6, l = t & 63;
        const int wm = wid >> 1, wn = wid & 1;      // wm 0..3 (32 rows), wn 0..1 (64 cols)
        const int q = l >> 4, lm = l & 15;
        const float* W1g = W1 + ((size_t)g * 512 + (size_t)mt * 128) * 256;
        const float* W2g = W2 + (size_t)g * 256 * 128;
        f32x4 acc[2][4];
        #pragma unroll
        for (int mi = 0; mi < 2; ++mi)
            #pragma unroll
            for (int ni = 0; ni < 4; ++ni) {
                f32x4 z = {0.f, 0.f, 0.f, 0.f};
                acc[mi][ni] = z;
            }
        for (int kt = 0; kt < 8; ++kt) {
            __syncthreads();
            #pragma unroll
            for (int i = 0; i < 2; ++i) {          // A: 128 x 32 f32 -> bf16
                int f4 = t + i * 512;
                int m = f4 >> 3, c4 = f4 & 7;
                f32x4 v = *(const f32x4*)(W1g + (size_t)m * 256 + kt * 32 + c4 * 4);
                *(uint64_t*)&As[m * 40 + c4 * 4] = pack4bf(v);
            }
            #pragma unroll
            for (int i = 0; i < 2; ++i) {          // B: 32(h) x 128(n)
                int f4 = t + i * 512;
                int h = f4 >> 5, n4 = f4 & 31;
                f32x4 v = *(const f32x4*)(W2g + (size_t)(kt * 32 + h) * 128 + n4 * 4);
                *(uint64_t*)&Bs[h * 132 + n4 * 4] = pack4bf(v);
            }
            __syncthreads();
            bf16x8 a[2];
            #pragma unroll
            for (int mi = 0; mi < 2; ++mi)
                a[mi] = *(const bf16x8*)&As[(wm * 32 + mi * 16 + lm) * 40 + q * 8];
            #pragma unroll
            for (int ni = 0; ni < 4; ++ni) {
                int n = wn * 64 + ni * 16 + lm;
                u16x8 bu;
                #pragma unroll
                for (int j = 0; j < 8; ++j) bu[j] = Bs[(q * 8 + j) * 132 + n];
                bf16x8 bv = __builtin_bit_cast(bf16x8, bu);
                #pragma unroll
                for (int mi = 0; mi < 2; ++mi)
                    acc[mi][ni] = __builtin_amdgcn_mfma_f32_16x16x32_bf16(a[mi], bv, acc[mi][ni], 0, 0, 0);
            }
        }
        uint16_t* Wcg = Wc + (size_t)g * 128 * 512;
        #pragma unroll
        for (int mi = 0; mi < 2; ++mi) {
            int k0 = mt * 128 + wm * 32 + mi * 16 + q * 4;
            #pragma unroll
            for (int ni = 0; ni < 4; ++ni) {
                int n = wn * 64 + ni * 16 + lm;
                f32x4 c = acc[mi][ni];
                *(uint64_t*)&Wcg[(size_t)n * 512 + k0] = pack4bf(c);
            }
        }
    } else if (bid < 320) {
        // ---- bias2[g][n] = b1[g] @ W2[g,:,n] + b2[g][n] ----
        if (t < 128) {
            const int g = bid - 256, n = t;
            const float* w = W2 + (size_t)g * 256 * 128 + n;
            const float* bb = b1 + g * 256;
            float s = b2[g * 128 + n];
            for (int h = 0; h < 256; ++h) s += bb[h] * w[(size_t)h * 128];
            bias2[g * 128 + n] = s;
        }
    } else {
        // ---- gather: stage x[b,:] as bf16 in LDS, then 32768 LDS gathers ----
        uint16_t* sh = (uint16_t*)smem8;            // [20000]
        const int b = bid - 320;
        const f32x4* xr = (const f32x4*)(x + (size_t)b * 20000);
        for (int i = t; i < 5000; i += 512) {
            f32x4 v = xr[i];
            *(uint64_t*)&sh[i * 4] = pack4bf(v);
        }
        __syncthreads();
        const int4* idx4 = (const int4*)idx;
        const size_t bbase = (size_t)b * 256;
        #pragma unroll 4
        for (int i = t; i < 8192; i += 512) {       // i indexes (g, k-quad)
            int4 iv = idx4[i];
            uint32_t w0 = (uint32_t)sh[iv.x] | ((uint32_t)sh[iv.y] << 16);
            uint32_t w1 = (uint32_t)sh[iv.z] | ((uint32_t)sh[iv.w] << 16);
            int g = i >> 7, kq = i & 127;
            uint2 p; p.x = w0; p.y = w1;
            *(uint2*)&G32[(size_t)g * 262144 + bbase + kq * 2] = p;
        }
    }
}

// ---------------- K4: out[b, g*128+n] = G[g] @ Wc[g]^T + bias2[g] ----------------
// m97-style: 128x128 tile, BK=64, global_load_lds(16), linear LDS [row][64] with
// XOR swizzle baked into the per-lane GLOBAL source (rule #21), swizzled ds_read.
__global__ __launch_bounds__(256) void k_gemm(const uint16_t* __restrict__ G,
                                              const uint16_t* __restrict__ Wc,
                                              const float* __restrict__ bias2,
                                              float* __restrict__ out) {
    __shared__ uint16_t sh[16384];             // A: [0,8192), B: [8192,16384) elems
    uint16_t* As = sh;
    uint16_t* Bs = sh + 8192;
    const int g = blockIdx.x >> 3, mt = blockIdx.x & 7;
    const int t = threadIdx.x;
    const int wid = t >> 6, l = t & 63;
    const int wm = wid >> 1, wn = wid & 1;
    const int q = l >> 4, lm = l & 15;
    const int lrow = l >> 3;                     // 8 rows per 1KB chunk
    const int lcolsw = ((l & 7) ^ lrow) * 8;     // inverse-swizzled global col (elems)
    const uint16_t* Ga = G + (size_t)g * 524288 + (size_t)mt * 128 * 512;
    const uint16_t* Wa = Wc + (size_t)g * 65536;

    f32x4 acc[4][4];
    #pragma unroll
    for (int mi = 0; mi < 4; ++mi)
        #pragma unroll
        for (int ni = 0; ni < 4; ++ni) {
            f32x4 z = {0.f, 0.f, 0.f, 0.f};
            acc[mi][ni] = z;
        }

    for (int kt = 0; kt < 8; ++kt) {
        __syncthreads();                          // prev compute done before overwrite
        #pragma unroll
        for (int r = 0; r < 4; ++r) {
            const int rowbase = wid * 8 + r * 32; // wave-uniform, multiple of 8
            const uint16_t* sA = Ga + (size_t)(rowbase + lrow) * 512 + kt * 64 + lcolsw;
            const uint16_t* sB = Wa + (size_t)(rowbase + lrow) * 512 + kt * 64 + lcolsw;
            __builtin_amdgcn_global_load_lds(
                (const __attribute__((address_space(1))) void*)sA,
                (__attribute__((address_space(3))) void*)(As + rowbase * 64), 16, 0, 0);
            __builtin_amdgcn_global_load_lds(
                (const __attribute__((address_space(1))) void*)sB,
                (__attribute__((address_space(3))) void*)(Bs + rowbase * 64), 16, 0, 0);
        }
        __syncthreads();                          // drains vmcnt -> data visible
        #pragma unroll
        for (int kk = 0; kk < 2; ++kk) {
            bf16x8 a[4], b[4];
            #pragma unroll
            for (int mi = 0; mi < 4; ++mi) {
                int row = wm * 64 + mi * 16 + lm;
                int off = row * 64 + ((kk * 32 + q * 8) ^ ((lm & 7) * 8));
                a[mi] = *(const bf16x8*)&As[off];
            }
            #pragma unroll
            for (int ni = 0; ni < 4; ++ni) {
                int row = wn * 64 + ni * 16 + lm;
                int off = row * 64 + ((kk * 32 + q * 8) ^ ((lm & 7) * 8));
                b[ni] = *(const bf16x8*)&Bs[off];
            }
            #pragma unroll
            for (int mi = 0; mi < 4; ++mi)
                #pragma unroll
                for (int ni = 0; ni < 4; ++ni)
                    acc[mi][ni] = __builtin_amdgcn_mfma_f32_16x16x32_bf16(a[mi], b[ni], acc[mi][ni], 0, 0, 0);
        }
    }
    // epilogue: C/D layout col=lane&15, row=(lane>>4)*4+reg
    float bn[4];
    #pragma unroll
    for (int ni = 0; ni < 4; ++ni) bn[ni] = bias2[g * 128 + wn * 64 + ni * 16 + lm];
    #pragma unroll
    for (int mi = 0; mi < 4; ++mi)
        #pragma unroll
        for (int ni = 0; ni < 4; ++ni) {
            int col = g * 128 + wn * 64 + ni * 16 + lm;
            #pragma unroll
            for (int r = 0; r < 4; ++r) {
                int brow = mt * 128 + wm * 64 + mi * 16 + q * 4 + r;
                out[(size_t)brow * 8192 + col] = acc[mi][ni][r] + bn[ni];
            }
        }
}

extern "C" void kernel_launch(void* const* d_in, const int* in_sizes, int n_in,
                              void* d_out, int out_size, void* d_ws, size_t ws_size,
                              hipStream_t stream) {
    (void)in_sizes; (void)n_in; (void)out_size; (void)ws_size;
    const float* x   = (const float*)d_in[0];
    const int*   idx = (const int*)d_in[1];
    const float* W1  = (const float*)d_in[2];
    const float* b1  = (const float*)d_in[3];
    const float* W2  = (const float*)d_in[4];
    const float* b2  = (const float*)d_in[5];
    float* out = (float*)d_out;

    uint16_t* G     = (uint16_t*)d_ws;                                  // 64 MiB
    uint16_t* Wc    = (uint16_t*)((char*)d_ws + (size_t)(64 << 20));    //  8 MiB
    float*    bias2 = (float*)   ((char*)d_ws + (size_t)(72 << 20));    // 32 KiB

    k_prep<<<1344, 512, 0, stream>>>(x, idx, W1, b1, W2, b2, Wc, bias2, (uint32_t*)G);
    k_gemm<<<512,  256, 0, stream>>>(G, Wc, bias2, out);
}

// Round 3
// 69.294 us; speedup vs baseline: 1.1261x; 1.0146x over previous
//
#include <hip/hip_runtime.h>
#include <hip/hip_bf16.h>
#include <stdint.h>

// Problem: B=1024, IN=20000, NG=64, GIN=512, H1=256, GS=128
// o = x[:,idx] @ (W1@W2) + (b1@W2 + b2)   -- linear-linear collapse
//
// ws layout: G bf16 [64][1024][512] @0 (64MiB), Wc bf16 [64][128][512] @64MiB (8MiB),
//            bias2 f32 [64][128] @72MiB (32KB). Requires ws_size >= 72MiB+32KB.
//
// R3: gather pipelined through registers (2 rows/block, prefetch row b1 during
// gather of b0) at 1024 thr, VGPR<=64 for 2 blocks/CU = 32 waves. wprep retiled
// to 1024 thr. k_gemm + bijective XCD swizzle.

typedef __attribute__((ext_vector_type(4))) float f32x4;
typedef __attribute__((ext_vector_type(8))) __bf16 bf16x8;
typedef __attribute__((ext_vector_type(8))) uint16_t u16x8;

__device__ __forceinline__ uint16_t f2bf(float f) {
    uint32_t u = __float_as_uint(f);
    u += 0x7FFFu + ((u >> 16) & 1u);   // RNE
    return (uint16_t)(u >> 16);
}

__device__ __forceinline__ uint64_t pack4bf(f32x4 v) {
    return (uint64_t)f2bf(v[0]) | ((uint64_t)f2bf(v[1]) << 16)
         | ((uint64_t)f2bf(v[2]) << 32) | ((uint64_t)f2bf(v[3]) << 48);
}

// ---- gather helpers: row = 20000 f32 = 5000 f32x4; 1024 threads ----
__device__ __forceinline__ void row_load(const float* __restrict__ xrow, int t, f32x4 r[5]) {
    #pragma unroll
    for (int i = 0; i < 5; ++i) {
        int si = t + i * 1024;
        si = si < 4999 ? si : 4999;          // clamp: no OOB, padding lanes duplicate
        r[i] = *(const f32x4*)(xrow + (size_t)si * 4);
    }
}

__device__ __forceinline__ void row_write(uint16_t* sh, int t, const f32x4 r[5]) {
    #pragma unroll
    for (int i = 0; i < 5; ++i) {
        int si = t + i * 1024;
        if (si < 5000) *(uint64_t*)&sh[si * 4] = pack4bf(r[i]);
    }
}

// 8192 uint2 items per row; item j: g=j>>7, kd=j&127; idx4[j] = 4 indices
__device__ __forceinline__ void row_gather(const uint16_t* sh, const int4* __restrict__ idx4,
                                           int t, int b, uint32_t* __restrict__ G32) {
    int4 nv = idx4[t];
    #pragma unroll
    for (int it = 0; it < 8; ++it) {
        int4 cv = nv;
        if (it < 7) nv = idx4[t + (it + 1) * 1024];
        int j = t + it * 1024;
        uint32_t w0 = (uint32_t)sh[cv.x] | ((uint32_t)sh[cv.y] << 16);
        uint32_t w1 = (uint32_t)sh[cv.z] | ((uint32_t)sh[cv.w] << 16);
        int g = j >> 7, kd = j & 127;
        uint2 p; p.x = w0; p.y = w1;
        *(uint2*)&G32[(size_t)g * 262144 + (size_t)b * 256 + kd * 2] = p;
    }
}

// ---------------- fat prep kernel (1024 threads) ----------------
// blocks [0,256):   wprep  -- Wc[g][n][k] = (W1[g]@W2[g])^T bf16, g=bid>>2, mt=bid&3
// blocks [256,320): bias   -- bias2[g][n] = b1[g]@W2[g,:,n] + b2[g][n]
// blocks [320,832): gather -- rows 2*(bid-320), 2*(bid-320)+1, reg-pipelined
__global__ __launch_bounds__(1024, 8) void k_prep(const float* __restrict__ x,
                                                  const int* __restrict__ idx,
                                                  const float* __restrict__ W1,
                                                  const float* __restrict__ b1,
                                                  const float* __restrict__ W2,
                                                  const float* __restrict__ b2,
                                                  uint16_t* __restrict__ Wc,
                                                  float* __restrict__ bias2,
                                                  uint32_t* __restrict__ G32) {
    __shared__ __align__(16) uint8_t smem[40960];
    const int bid = blockIdx.x;
    const int t = threadIdx.x;

    if (bid < 256) {
        // ---- wprep: 16 waves as 4x4; wave tile 32(m=k of Wc^T) x 32(n); BK=32 ----
        uint16_t* As = (uint16_t*)smem;             // [128][40]
        uint16_t* Bs = As + 5120;                   // [32][132]
        const int g = bid >> 2, mt = bid & 3;
        const int wid = t >> 6, l = t & 63;
        const int wm = wid >> 2, wn = wid & 3;
        const int q = l >> 4, lm = l & 15;
        const float* W1g = W1 + ((size_t)g * 512 + (size_t)mt * 128) * 256;
        const float* W2g = W2 + (size_t)g * 256 * 128;
        f32x4 acc[2][2];
        #pragma unroll
        for (int mi = 0; mi < 2; ++mi)
            #pragma unroll
            for (int ni = 0; ni < 2; ++ni) {
                f32x4 z = {0.f, 0.f, 0.f, 0.f};
                acc[mi][ni] = z;
            }
        for (int kt = 0; kt < 8; ++kt) {
            __syncthreads();
            {   // A: 128 x 32 f32 -> bf16 (1024 f32x4, 1/thread)
                int m = t >> 3, c4 = t & 7;
                f32x4 v = *(const f32x4*)(W1g + (size_t)m * 256 + kt * 32 + c4 * 4);
                *(uint64_t*)&As[m * 40 + c4 * 4] = pack4bf(v);
            }
            {   // B: 32(h) x 128(n)
                int h = t >> 5, n4 = t & 31;
                f32x4 v = *(const f32x4*)(W2g + (size_t)(kt * 32 + h) * 128 + n4 * 4);
                *(uint64_t*)&Bs[h * 132 + n4 * 4] = pack4bf(v);
            }
            __syncthreads();
            bf16x8 a[2];
            #pragma unroll
            for (int mi = 0; mi < 2; ++mi)
                a[mi] = *(const bf16x8*)&As[(wm * 32 + mi * 16 + lm) * 40 + q * 8];
            #pragma unroll
            for (int ni = 0; ni < 2; ++ni) {
                int n = wn * 32 + ni * 16 + lm;
                u16x8 bu;
                #pragma unroll
                for (int j = 0; j < 8; ++j) bu[j] = Bs[(q * 8 + j) * 132 + n];
                bf16x8 bv = __builtin_bit_cast(bf16x8, bu);
                #pragma unroll
                for (int mi = 0; mi < 2; ++mi)
                    acc[mi][ni] = __builtin_amdgcn_mfma_f32_16x16x32_bf16(a[mi], bv, acc[mi][ni], 0, 0, 0);
            }
        }
        uint16_t* Wcg = Wc + (size_t)g * 128 * 512;
        #pragma unroll
        for (int mi = 0; mi < 2; ++mi) {
            int k0 = mt * 128 + wm * 32 + mi * 16 + q * 4;
            #pragma unroll
            for (int ni = 0; ni < 2; ++ni) {
                int n = wn * 32 + ni * 16 + lm;
                *(uint64_t*)&Wcg[(size_t)n * 512 + k0] = pack4bf(acc[mi][ni]);
            }
        }
    } else if (bid < 320) {
        // ---- bias2[g][n] = b1[g] @ W2[g,:,n] + b2[g][n] ----
        if (t < 128) {
            const int g = bid - 256, n = t;
            const float* w = W2 + (size_t)g * 256 * 128 + n;
            const float* bb = b1 + g * 256;
            float s = b2[g * 128 + n];
            for (int h = 0; h < 256; ++h) s += bb[h] * w[(size_t)h * 128];
            bias2[g * 128 + n] = s;
        }
    } else {
        // ---- gather: 2 rows, register-pipelined ----
        uint16_t* sh = (uint16_t*)smem;              // 20480 bf16 (pad 20000->20480)
        const int gb = bid - 320;
        const int b0 = gb * 2, b1r = b0 + 1;
        const int4* idx4 = (const int4*)idx;
        f32x4 r[5];
        row_load(x + (size_t)b0 * 20000, t, r);
        row_write(sh, t, r);
        __syncthreads();
        row_load(x + (size_t)b1r * 20000, t, r);     // issue b1 loads early
        __builtin_amdgcn_sched_barrier(0);           // pin issue before gather
        row_gather(sh, idx4, t, b0, G32);            // HBM latency hides here
        __syncthreads();                             // all reads of sh done
        row_write(sh, t, r);                         // waitcnt on b1 loads here
        __syncthreads();
        row_gather(sh, idx4, t, b1r, G32);
    }
}

// ---------------- K2: out[b, g*128+n] = G[g] @ Wc[g]^T + bias2[g] ----------------
// m97-style: 128x128 tile, BK=64, global_load_lds(16), linear LDS, XOR swizzle
// via pre-swizzled global source (rule #21). Bijective XCD swizzle (512%8==0).
__global__ __launch_bounds__(256) void k_gemm(const uint16_t* __restrict__ G,
                                              const uint16_t* __restrict__ Wc,
                                              const float* __restrict__ bias2,
                                              float* __restrict__ out) {
    __shared__ uint16_t sh[16384];             // A: [0,8192), B: [8192,16384) elems
    uint16_t* As = sh;
    uint16_t* Bs = sh + 8192;
    const int wg = (blockIdx.x & 7) * 64 + (blockIdx.x >> 3);   // XCD swizzle
    const int g = wg >> 3, mt = wg & 7;
    const int t = threadIdx.x;
    const int wid = t >> 6, l = t & 63;
    const int wm = wid >> 1, wn = wid & 1;
    const int q = l >> 4, lm = l & 15;
    const int lrow = l >> 3;                     // 8 rows per 1KB chunk
    const int lcolsw = ((l & 7) ^ lrow) * 8;     // inverse-swizzled global col (elems)
    const uint16_t* Ga = G + (size_t)g * 524288 + (size_t)mt * 128 * 512;
    const uint16_t* Wa = Wc + (size_t)g * 65536;

    f32x4 acc[4][4];
    #pragma unroll
    for (int mi = 0; mi < 4; ++mi)
        #pragma unroll
        for (int ni = 0; ni < 4; ++ni) {
            f32x4 z = {0.f, 0.f, 0.f, 0.f};
            acc[mi][ni] = z;
        }

    for (int kt = 0; kt < 8; ++kt) {
        __syncthreads();                          // prev compute done before overwrite
        #pragma unroll
        for (int r = 0; r < 4; ++r) {
            const int rowbase = wid * 8 + r * 32; // wave-uniform, multiple of 8
            const uint16_t* sA = Ga + (size_t)(rowbase + lrow) * 512 + kt * 64 + lcolsw;
            const uint16_t* sB = Wa + (size_t)(rowbase + lrow) * 512 + kt * 64 + lcolsw;
            __builtin_amdgcn_global_load_lds(
                (const __attribute__((address_space(1))) void*)sA,
                (__attribute__((address_space(3))) void*)(As + rowbase * 64), 16, 0, 0);
            __builtin_amdgcn_global_load_lds(
                (const __attribute__((address_space(1))) void*)sB,
                (__attribute__((address_space(3))) void*)(Bs + rowbase * 64), 16, 0, 0);
        }
        __syncthreads();                          // drains vmcnt -> data visible
        #pragma unroll
        for (int kk = 0; kk < 2; ++kk) {
            bf16x8 a[4], b[4];
            #pragma unroll
            for (int mi = 0; mi < 4; ++mi) {
                int row = wm * 64 + mi * 16 + lm;
                int off = row * 64 + ((kk * 32 + q * 8) ^ ((lm & 7) * 8));
                a[mi] = *(const bf16x8*)&As[off];
            }
            #pragma unroll
            for (int ni = 0; ni < 4; ++ni) {
                int row = wn * 64 + ni * 16 + lm;
                int off = row * 64 + ((kk * 32 + q * 8) ^ ((lm & 7) * 8));
                b[ni] = *(const bf16x8*)&Bs[off];
            }
            #pragma unroll
            for (int mi = 0; mi < 4; ++mi)
                #pragma unroll
                for (int ni = 0; ni < 4; ++ni)
                    acc[mi][ni] = __builtin_amdgcn_mfma_f32_16x16x32_bf16(a[mi], b[ni], acc[mi][ni], 0, 0, 0);
        }
    }
    // epilogue: C/D layout col=lane&15, row=(lane>>4)*4+reg
    float bn[4];
    #pragma unroll
    for (int ni = 0; ni < 4; ++ni) bn[ni] = bias2[g * 128 + wn * 64 + ni * 16 + lm];
    #pragma unroll
    for (int mi = 0; mi < 4; ++mi)
        #pragma unroll
        for (int ni = 0; ni < 4; ++ni) {
            int col = g * 128 + wn * 64 + ni * 16 + lm;
            #pragma unroll
            for (int r = 0; r < 4; ++r) {
                int brow = mt * 128 + wm * 64 + mi * 16 + q * 4 + r;
                out[(size_t)brow * 8192 + col] = acc[mi][ni][r] + bn[ni];
            }
        }
}

extern "C" void kernel_launch(void* const* d_in, const int* in_sizes, int n_in,
                              void* d_out, int out_size, void* d_ws, size_t ws_size,
                              hipStream_t stream) {
    (void)in_sizes; (void)n_in; (void)out_size; (void)ws_size;
    const float* x   = (const float*)d_in[0];
    const int*   idx = (const int*)d_in[1];
    const float* W1  = (const float*)d_in[2];
    const float* b1  = (const float*)d_in[3];
    const float* W2  = (const float*)d_in[4];
    const float* b2  = (const float*)d_in[5];
    float* out = (float*)d_out;

    uint16_t* G     = (uint16_t*)d_ws;                                  // 64 MiB
    uint16_t* Wc    = (uint16_t*)((char*)d_ws + (size_t)(64 << 20));    //  8 MiB
    float*    bias2 = (float*)   ((char*)d_ws + (size_t)(72 << 20));    // 32 KiB

    k_prep<<<832, 1024, 0, stream>>>(x, idx, W1, b1, W2, b2, Wc, bias2, (uint32_t*)G);
    k_gemm<<<512,  256, 0, stream>>>(G, Wc, bias2, out);
}

// Round 5
// 58.313 us; speedup vs baseline: 1.3381x; 1.1883x over previous
//
#include <hip/hip_runtime.h>
#include <hip/hip_bf16.h>
#include <stdint.h>

// Problem: B=1024, IN=20000, NG=64, GIN=512, H1=256, GS=128
// o = x[:,idx] @ (W1@W2) + (b1@W2 + b2)   -- linear-linear collapse
//
// ws layout: G bf16 [64][1024][512] @0 (64MiB), Wc bf16 [64][128][512] @64MiB (8MiB),
//            bias2 f32 [64][128] @72MiB (32KB). Requires ws_size >= 72MiB+32KB.
//
// R5: R4 with the staging-count bug fixed: x-row = 5000 16B chunks -> 5 DMA
// issues x 1024 threads (tail clamped into LDS pad). Wave-uniform LDS dest.

typedef __attribute__((ext_vector_type(4))) float f32x4;
typedef __attribute__((ext_vector_type(8))) __bf16 bf16x8;
typedef __attribute__((ext_vector_type(8))) uint16_t u16x8;

__device__ __forceinline__ uint16_t f2bf(float f) {
    uint32_t u = __float_as_uint(f);
    u += 0x7FFFu + ((u >> 16) & 1u);   // RNE
    return (uint16_t)(u >> 16);
}

__device__ __forceinline__ uint64_t pack4bf(f32x4 v) {
    return (uint64_t)f2bf(v[0]) | ((uint64_t)f2bf(v[1]) << 16)
         | ((uint64_t)f2bf(v[2]) << 32) | ((uint64_t)f2bf(v[3]) << 48);
}

// ---------------- fat prep kernel (1024 threads) ----------------
// blocks [0,256):    wprep  -- Wc[g][n][k] = (W1[g]@W2[g])^T bf16, g=bid>>2, mt=bid&3
// blocks [256,320):  bias   -- bias2[g][n] = b1[g]@W2[g,:,n] + b2[g][n]
// blocks [320,1344): gather -- row b=bid-320: DMA x-row f32 into LDS, gather+cvt
__global__ __launch_bounds__(1024, 8) void k_prep(const float* __restrict__ x,
                                                  const int* __restrict__ idx,
                                                  const float* __restrict__ W1,
                                                  const float* __restrict__ b1,
                                                  const float* __restrict__ W2,
                                                  const float* __restrict__ b2,
                                                  uint16_t* __restrict__ Wc,
                                                  float* __restrict__ bias2,
                                                  uint32_t* __restrict__ G32) {
    __shared__ __align__(16) uint8_t smem[81920];   // gather: f32 row, 5120 chunks
    const int bid = blockIdx.x;
    const int t = threadIdx.x;

    if (bid < 256) {
        // ---- wprep: 16 waves as 4x4; wave tile 32(m=k of Wc^T) x 32(n); BK=32 ----
        uint16_t* As = (uint16_t*)smem;             // [128][40]
        uint16_t* Bs = As + 5120;                   // [32][132]
        const int g = bid >> 2, mt = bid & 3;
        const int wid = t >> 6, l = t & 63;
        const int wm = wid >> 2, wn = wid & 3;
        const int q = l >> 4, lm = l & 15;
        const float* W1g = W1 + ((size_t)g * 512 + (size_t)mt * 128) * 256;
        const float* W2g = W2 + (size_t)g * 256 * 128;
        f32x4 acc[2][2];
        #pragma unroll
        for (int mi = 0; mi < 2; ++mi)
            #pragma unroll
            for (int ni = 0; ni < 2; ++ni) {
                f32x4 z = {0.f, 0.f, 0.f, 0.f};
                acc[mi][ni] = z;
            }
        for (int kt = 0; kt < 8; ++kt) {
            __syncthreads();
            {   // A: 128 x 32 f32 -> bf16 (1024 f32x4, 1/thread)
                int m = t >> 3, c4 = t & 7;
                f32x4 v = *(const f32x4*)(W1g + (size_t)m * 256 + kt * 32 + c4 * 4);
                *(uint64_t*)&As[m * 40 + c4 * 4] = pack4bf(v);
            }
            {   // B: 32(h) x 128(n)
                int h = t >> 5, n4 = t & 31;
                f32x4 v = *(const f32x4*)(W2g + (size_t)(kt * 32 + h) * 128 + n4 * 4);
                *(uint64_t*)&Bs[h * 132 + n4 * 4] = pack4bf(v);
            }
            __syncthreads();
            bf16x8 a[2];
            #pragma unroll
            for (int mi = 0; mi < 2; ++mi)
                a[mi] = *(const bf16x8*)&As[(wm * 32 + mi * 16 + lm) * 40 + q * 8];
            #pragma unroll
            for (int ni = 0; ni < 2; ++ni) {
                int n = wn * 32 + ni * 16 + lm;
                u16x8 bu;
                #pragma unroll
                for (int j = 0; j < 8; ++j) bu[j] = Bs[(q * 8 + j) * 132 + n];
                bf16x8 bv = __builtin_bit_cast(bf16x8, bu);
                #pragma unroll
                for (int mi = 0; mi < 2; ++mi)
                    acc[mi][ni] = __builtin_amdgcn_mfma_f32_16x16x32_bf16(a[mi], bv, acc[mi][ni], 0, 0, 0);
            }
        }
        uint16_t* Wcg = Wc + (size_t)g * 128 * 512;
        #pragma unroll
        for (int mi = 0; mi < 2; ++mi) {
            int k0 = mt * 128 + wm * 32 + mi * 16 + q * 4;
            #pragma unroll
            for (int ni = 0; ni < 2; ++ni) {
                int n = wn * 32 + ni * 16 + lm;
                *(uint64_t*)&Wcg[(size_t)n * 512 + k0] = pack4bf(acc[mi][ni]);
            }
        }
    } else if (bid < 320) {
        // ---- bias2[g][n] = b1[g] @ W2[g,:,n] + b2[g][n] ----
        if (t < 128) {
            const int g = bid - 256, n = t;
            const float* w = W2 + (size_t)g * 256 * 128 + n;
            const float* bb = b1 + g * 256;
            float s = b2[g * 128 + n];
            for (int h = 0; h < 256; ++h) s += bb[h] * w[(size_t)h * 128];
            bias2[g * 128 + n] = s;
        }
    } else {
        // ---- gather: one row; stage f32 via global_load_lds DMA ----
        float* shf = (float*)smem;                   // 20480 f32 (20000 + pad)
        const int b = bid - 320;
        const float* xrow = x + (size_t)b * 20000;
        const int wb = (t >> 6) << 6;                // first tid of my wave (uniform)
        // 5000 16B chunks; 5 issues x 1024 threads = 5120 (tail source-clamped,
        // dests land in LDS pad [80000, 81920))
        #pragma unroll
        for (int i = 0; i < 5; ++i) {
            int c = t + i * 1024;                    // this lane's chunk
            int csrc = c < 5000 ? c : 4999;          // per-lane global src (clamped)
            __builtin_amdgcn_global_load_lds(
                (const __attribute__((address_space(1))) void*)(xrow + (size_t)csrc * 4),
                (__attribute__((address_space(3))) void*)(shf + (size_t)(wb + i * 1024) * 4),
                16, 0, 0);                           // wave-uniform LDS base + lane*16
        }
        __syncthreads();                             // vmcnt(0) drain: row visible
        const int4* idx4 = (const int4*)idx;
        int4 nv = idx4[t];
        #pragma unroll
        for (int it = 0; it < 8; ++it) {
            int4 cv = nv;
            if (it < 7) nv = idx4[t + (it + 1) * 1024];
            float f0 = shf[cv.x], f1 = shf[cv.y], f2 = shf[cv.z], f3 = shf[cv.w];
            uint32_t w0, w1;
            asm("v_cvt_pk_bf16_f32 %0, %1, %2" : "=v"(w0) : "v"(f0), "v"(f1));
            asm("v_cvt_pk_bf16_f32 %0, %1, %2" : "=v"(w1) : "v"(f2), "v"(f3));
            int j = t + it * 1024;
            int g = j >> 7, kd = j & 127;
            uint2 p; p.x = w0; p.y = w1;
            *(uint2*)&G32[(size_t)g * 262144 + (size_t)b * 256 + kd * 2] = p;
        }
    }
}

// ---------------- K2: out[b, g*128+n] = G[g] @ Wc[g]^T + bias2[g] ----------------
// m97-style: 128x128 tile, BK=64, global_load_lds(16), linear LDS, XOR swizzle
// via pre-swizzled global source (rule #21). Bijective XCD swizzle (512%8==0).
__global__ __launch_bounds__(256) void k_gemm(const uint16_t* __restrict__ G,
                                              const uint16_t* __restrict__ Wc,
                                              const float* __restrict__ bias2,
                                              float* __restrict__ out) {
    __shared__ uint16_t sh[16384];             // A: [0,8192), B: [8192,16384) elems
    uint16_t* As = sh;
    uint16_t* Bs = sh + 8192;
    const int wg = (blockIdx.x & 7) * 64 + (blockIdx.x >> 3);   // XCD swizzle
    const int g = wg >> 3, mt = wg & 7;
    const int t = threadIdx.x;
    const int wid = t >> 6, l = t & 63;
    const int wm = wid >> 1, wn = wid & 1;
    const int q = l >> 4, lm = l & 15;
    const int lrow = l >> 3;                     // 8 rows per 1KB chunk
    const int lcolsw = ((l & 7) ^ lrow) * 8;     // inverse-swizzled global col (elems)
    const uint16_t* Ga = G + (size_t)g * 524288 + (size_t)mt * 128 * 512;
    const uint16_t* Wa = Wc + (size_t)g * 65536;

    f32x4 acc[4][4];
    #pragma unroll
    for (int mi = 0; mi < 4; ++mi)
        #pragma unroll
        for (int ni = 0; ni < 4; ++ni) {
            f32x4 z = {0.f, 0.f, 0.f, 0.f};
            acc[mi][ni] = z;
        }

    for (int kt = 0; kt < 8; ++kt) {
        __syncthreads();                          // prev compute done before overwrite
        #pragma unroll
        for (int r = 0; r < 4; ++r) {
            const int rowbase = wid * 8 + r * 32; // wave-uniform, multiple of 8
            const uint16_t* sA = Ga + (size_t)(rowbase + lrow) * 512 + kt * 64 + lcolsw;
            const uint16_t* sB = Wa + (size_t)(rowbase + lrow) * 512 + kt * 64 + lcolsw;
            __builtin_amdgcn_global_load_lds(
                (const __attribute__((address_space(1))) void*)sA,
                (__attribute__((address_space(3))) void*)(As + rowbase * 64), 16, 0, 0);
            __builtin_amdgcn_global_load_lds(
                (const __attribute__((address_space(1))) void*)sB,
                (__attribute__((address_space(3))) void*)(Bs + rowbase * 64), 16, 0, 0);
        }
        __syncthreads();                          // drains vmcnt -> data visible
        #pragma unroll
        for (int kk = 0; kk < 2; ++kk) {
            bf16x8 a[4], b[4];
            #pragma unroll
            for (int mi = 0; mi < 4; ++mi) {
                int row = wm * 64 + mi * 16 + lm;
                int off = row * 64 + ((kk * 32 + q * 8) ^ ((lm & 7) * 8));
                a[mi] = *(const bf16x8*)&As[off];
            }
            #pragma unroll
            for (int ni = 0; ni < 4; ++ni) {
                int row = wn * 64 + ni * 16 + lm;
                int off = row * 64 + ((kk * 32 + q * 8) ^ ((lm & 7) * 8));
                b[ni] = *(const bf16x8*)&Bs[off];
            }
            #pragma unroll
            for (int mi = 0; mi < 4; ++mi)
                #pragma unroll
                for (int ni = 0; ni < 4; ++ni)
                    acc[mi][ni] = __builtin_amdgcn_mfma_f32_16x16x32_bf16(a[mi], b[ni], acc[mi][ni], 0, 0, 0);
        }
    }
    // epilogue: C/D layout col=lane&15, row=(lane>>4)*4+reg
    float bn[4];
    #pragma unroll
    for (int ni = 0; ni < 4; ++ni) bn[ni] = bias2[g * 128 + wn * 64 + ni * 16 + lm];
    #pragma unroll
    for (int mi = 0; mi < 4; ++mi)
        #pragma unroll
        for (int ni = 0; ni < 4; ++ni) {
            int col = g * 128 + wn * 64 + ni * 16 + lm;
            #pragma unroll
            for (int r = 0; r < 4; ++r) {
                int brow = mt * 128 + wm * 64 + mi * 16 + q * 4 + r;
                out[(size_t)brow * 8192 + col] = acc[mi][ni][r] + bn[ni];
            }
        }
}

extern "C" void kernel_launch(void* const* d_in, const int* in_sizes, int n_in,
                              void* d_out, int out_size, void* d_ws, size_t ws_size,
                              hipStream_t stream) {
    (void)in_sizes; (void)n_in; (void)out_size; (void)ws_size;
    const float* x   = (const float*)d_in[0];
    const int*   idx = (const int*)d_in[1];
    const float* W1  = (const float*)d_in[2];
    const float* b1  = (const float*)d_in[3];
    const float* W2  = (const float*)d_in[4];
    const float* b2  = (const float*)d_in[5];
    float* out = (float*)d_out;

    uint16_t* G     = (uint16_t*)d_ws;                                  // 64 MiB
    uint16_t* Wc    = (uint16_t*)((char*)d_ws + (size_t)(64 << 20));    //  8 MiB
    float*    bias2 = (float*)   ((char*)d_ws + (size_t)(72 << 20));    // 32 KiB

    k_prep<<<1344, 1024, 0, stream>>>(x, idx, W1, b1, W2, b2, Wc, bias2, (uint32_t*)G);
    k_gemm<<<512,  256, 0, stream>>>(G, Wc, bias2, out);
}